// Round 1
// baseline (542.865 us; speedup 1.0000x reference)
//
#include <hip/hip_runtime.h>
#include <hip/hip_bf16.h>

#define B_ 2048
#define T_ 512
#define D_ 32
#define K_ 10
#define LN_EPS 1e-5f

// ws layout:
//   em   f32 [B][T][K]      @ 0           (41,943,040 B)
//   hist u8  [T][B][16]     @ 41943040    (16,777,216 B)
//   llh  f32 [B]            @ 58720256    (8,192 B)
//   last i32 [B]            @ 58728448    (8,192 B)

// ---------------- Phase 1: emissions = LN(x @ W^T + b) ----------------
__global__ __launch_bounds__(256) void emis_kernel(
    const float* __restrict__ x, const float* __restrict__ W,
    const float* __restrict__ bb, const float* __restrict__ gamma,
    const float* __restrict__ beta, float* __restrict__ em)
{
    __shared__ float sW[K_ * D_ + 3 * K_];
    for (int i = threadIdx.x; i < K_ * D_ + 3 * K_; i += blockDim.x) {
        float v;
        if (i < K_ * D_)            v = W[i];
        else if (i < K_ * D_ + K_)  v = bb[i - K_ * D_];
        else if (i < K_ * D_ + 2*K_) v = gamma[i - K_ * D_ - K_];
        else                         v = beta[i - K_ * D_ - 2 * K_];
        sW[i] = v;
    }
    __syncthreads();
    int row = blockIdx.x * blockDim.x + threadIdx.x;   // (b*T + t)
    if (row >= B_ * T_) return;
    const float4* xr = reinterpret_cast<const float4*>(x + (size_t)row * D_);
    float4 xv[8];
    #pragma unroll
    for (int i = 0; i < 8; i++) xv[i] = xr[i];
    float h[K_];
    #pragma unroll
    for (int k = 0; k < K_; k++) {
        float acc = 0.f;
        #pragma unroll
        for (int i = 0; i < 8; i++) {
            acc = fmaf(xv[i].x, sW[k * D_ + 4 * i + 0], acc);
            acc = fmaf(xv[i].y, sW[k * D_ + 4 * i + 1], acc);
            acc = fmaf(xv[i].z, sW[k * D_ + 4 * i + 2], acc);
            acc = fmaf(xv[i].w, sW[k * D_ + 4 * i + 3], acc);
        }
        h[k] = acc + sW[K_ * D_ + k];
    }
    float mu = 0.f;
    #pragma unroll
    for (int k = 0; k < K_; k++) mu += h[k];
    mu = mu / (float)K_;
    float var = 0.f;
    #pragma unroll
    for (int k = 0; k < K_; k++) { float d = h[k] - mu; var += d * d; }
    var = var / (float)K_;
    float r = 1.0f / sqrtf(var + LN_EPS);
    float e[K_];
    #pragma unroll
    for (int k = 0; k < K_; k++)
        e[k] = (h[k] - mu) * r * sW[K_ * D_ + K_ + k] + sW[K_ * D_ + 2 * K_ + k];
    float2* eo = reinterpret_cast<float2*>(em + (size_t)row * K_);
    #pragma unroll
    for (int k = 0; k < 5; k++) eo[k] = make_float2(e[2 * k], e[2 * k + 1]);
}

// ---------------- Phase 2: fused CRF-forward + Viterbi scan ----------------
// 64 threads = 1 wave = 4 groups of 16 lanes; group handles one sequence.
// Lane j<10 owns state j. Lane 10 accumulates the numerator score.
__global__ __launch_bounds__(64) void scan_kernel(
    const float* __restrict__ em, const int* __restrict__ labels,
    const int* __restrict__ mask, const float* __restrict__ startt,
    const float* __restrict__ endt, const float* __restrict__ trans,
    unsigned char* __restrict__ hist, float* __restrict__ llh_out,
    int* __restrict__ last_out)
{
    // share slab: stride 40 floats/group -> 16B-aligned b128 reads, groups on
    // disjoint bank quads {0,8,16,24}; v at [0..9], f at [16..25].
    __shared__ float sh[2][4][40];
    __shared__ float str[K_ * K_ + 2 * K_];  // trans(100), start(10), end(10)
    int lane = threadIdx.x;
    for (int i = lane; i < K_ * K_ + 2 * K_; i += 64) {
        float v;
        if (i < 100)      v = trans[i];
        else if (i < 110) v = startt[i - 100];
        else              v = endt[i - 110];
        str[i] = v;
    }
    __builtin_amdgcn_wave_barrier();   // single wave: in-order DS pipe orders write->read

    int g  = lane >> 4;
    int gl = lane & 15;
    int b  = blockIdx.x * 4 + g;
    int jj = gl < K_ ? gl : K_ - 1;    // clamped state index (lanes 10-15 shadow state 9)
    bool isState = gl < K_;

    float Tc[K_];                       // trans column for my state: Tc[i] = trans[i][jj]
    #pragma unroll
    for (int i = 0; i < K_; i++) Tc[i] = str[i * K_ + jj];

    const float* emb  = em + (size_t)b * T_ * K_;
    const int* labb   = labels + (size_t)b * T_;
    const int* maskb  = mask + (size_t)b * T_;

    // t = 0
    float em_cur = emb[jj];
    float v = str[100 + jj] + em_cur;   // score0 = start + em[:,0]
    float f = v;
    float num = 0.f; int prev = 0, cnt = 0;
    if (gl == 10) {
        int lab0 = labb[0];
        num  = startt[lab0] + emb[lab0];
        prev = lab0;
        cnt  = maskb[0];
    }
    sh[0][g][gl]      = v;
    sh[0][g][16 + gl] = f;
    __builtin_amdgcn_wave_barrier();
    float sv[K_], sf[K_];
    #pragma unroll
    for (int i = 0; i < K_; i++) { sv[i] = sh[0][g][i]; sf[i] = sh[0][g][16 + i]; }
    __builtin_amdgcn_wave_barrier();

    // prefetch t=1
    float em_n  = emb[K_ + jj];
    int   msk_n = maskb[1];
    int   lab_n = 0; float emtag_n = 0.f;
    if (gl == 10) { lab_n = labb[1]; emtag_n = emb[K_ + lab_n]; }

    for (int t = 1; t < T_; ++t) {
        int buf = t & 1;
        float em_t = em_n; int m_t = msk_n; int lab_t = lab_n; float emtag_t = emtag_n;
        int tn = (t + 1 < T_) ? t + 1 : T_ - 1;
        em_n  = emb[(size_t)tn * K_ + jj];
        msk_n = maskb[tn];
        if (gl == 10) { lab_n = labb[tn]; emtag_n = emb[(size_t)tn * K_ + lab_n]; }

        // Viterbi: exact f32 op order of ref (add, order-free max, first-max argmax)
        float best = sv[0] + Tc[0]; int bi = 0;
        #pragma unroll
        for (int i = 1; i < K_; i++) {
            float c = sv[i] + Tc[i];
            if (c > best) { best = c; bi = i; }
        }
        float vnew = best + em_t;

        // CRF forward (logsumexp) — loss tolerance is 2%, fast intrinsics fine
        float a[K_];
        #pragma unroll
        for (int i = 0; i < K_; i++) a[i] = sf[i] + Tc[i];
        float mx = a[0];
        #pragma unroll
        for (int i = 1; i < K_; i++) mx = fmaxf(mx, a[i]);
        float s = 0.f;
        #pragma unroll
        for (int i = 0; i < K_; i++) s += __expf(a[i] - mx);
        float fnew = em_t + (mx + __logf(s));

        v = vnew;
        f = (m_t > 0) ? fnew : f;

        if (isState) hist[((size_t)t * B_ + b) * 16 + gl] = (unsigned char)bi;

        if (gl == 10) {
            num += (str[prev * K_ + lab_t] + emtag_t) * (float)m_t;
            prev = lab_t;
            cnt += m_t;
        }

        sh[buf][g][gl]      = v;
        sh[buf][g][16 + gl] = f;
        __builtin_amdgcn_wave_barrier();
        #pragma unroll
        for (int i = 0; i < K_; i++) { sv[i] = sh[buf][g][i]; sf[i] = sh[buf][g][16 + i]; }
        __builtin_amdgcn_wave_barrier();
    }

    // epilogue
    if (gl == 0) {   // Viterbi terminal argmax
        float bestv = sv[0] + str[110 + 0]; int bi = 0;
        #pragma unroll
        for (int i = 1; i < K_; i++) {
            float c = sv[i] + str[110 + i];
            if (c > bestv) { bestv = c; bi = i; }
        }
        last_out[b] = bi;
    }
    if (gl == 10) {  // log_z and llh
        float aa[K_];
        #pragma unroll
        for (int i = 0; i < K_; i++) aa[i] = sf[i] + str[110 + i];
        float mx = aa[0];
        #pragma unroll
        for (int i = 1; i < K_; i++) mx = fmaxf(mx, aa[i]);
        float s = 0.f;
        #pragma unroll
        for (int i = 0; i < K_; i++) s += __expf(aa[i] - mx);
        float logz = mx + __logf(s);
        int last_tag = labb[cnt - 1];
        num += endt[last_tag];
        llh_out[b] = num - logz;
    }
}

// ---------------- Phase 3: backtrack ----------------
__global__ __launch_bounds__(256) void back_kernel(
    const unsigned char* __restrict__ hist, const int* __restrict__ last,
    float* __restrict__ path)
{
    int b = blockIdx.x * blockDim.x + threadIdx.x;
    if (b >= B_) return;
    int tag = last[b];
    path[(size_t)b * T_ + T_ - 1] = (float)tag;
    const int4* h4 = reinterpret_cast<const int4*>(hist);
    #pragma unroll 4
    for (int t = T_ - 1; t >= 1; --t) {
        int4 vv = h4[(size_t)t * B_ + b];   // load independent of tag chain
        int w = tag >> 2;
        int word = (w == 0) ? vv.x : ((w == 1) ? vv.y : ((w == 2) ? vv.z : vv.w));
        tag = (word >> ((tag & 3) * 8)) & 0xff;
        path[(size_t)b * T_ + t - 1] = (float)tag;
    }
}

// ---------------- Phase 4: loss reduction ----------------
__global__ __launch_bounds__(256) void loss_kernel(
    const float* __restrict__ llh, float* __restrict__ out)
{
    __shared__ float red[256];
    float s = 0.f;
    for (int i = threadIdx.x; i < B_; i += 256) s += llh[i];
    red[threadIdx.x] = s;
    __syncthreads();
    for (int off = 128; off > 0; off >>= 1) {
        if (threadIdx.x < off) red[threadIdx.x] += red[threadIdx.x + off];
        __syncthreads();
    }
    if (threadIdx.x == 0) out[0] = -red[0];
}

extern "C" void kernel_launch(void* const* d_in, const int* in_sizes, int n_in,
                              void* d_out, int out_size, void* d_ws, size_t ws_size,
                              hipStream_t stream)
{
    const float* x      = (const float*)d_in[0];
    const int*   labels = (const int*)d_in[1];
    const int*   mask   = (const int*)d_in[2];
    const float* W      = (const float*)d_in[3];
    const float* bb     = (const float*)d_in[4];
    const float* gamma  = (const float*)d_in[5];
    const float* beta   = (const float*)d_in[6];
    const float* startt = (const float*)d_in[7];
    const float* endt   = (const float*)d_in[8];
    const float* trans  = (const float*)d_in[9];
    float* out = (float*)d_out;

    char* ws = (char*)d_ws;
    float*         em   = (float*)ws;
    unsigned char* hist = (unsigned char*)(ws + 41943040);
    float*         llh  = (float*)(ws + 41943040 + 16777216);
    int*           last = (int*)(ws + 41943040 + 16777216 + 8192);

    emis_kernel<<<(B_ * T_) / 256, 256, 0, stream>>>(x, W, bb, gamma, beta, em);
    scan_kernel<<<B_ / 4, 64, 0, stream>>>(em, labels, mask, startt, endt, trans,
                                           hist, llh, last);
    back_kernel<<<B_ / 256, 256, 0, stream>>>(hist, last, out + 1);
    loss_kernel<<<1, 256, 0, stream>>>(llh, out);
}

// Round 2
// 475.403 us; speedup vs baseline: 1.1419x; 1.1419x over previous
//
#include <hip/hip_runtime.h>
#include <hip/hip_bf16.h>

#define B_ 2048
#define T_ 512
#define D_ 32
#define K_ 10
#define LN_EPS 1e-5f
#define CH_ 64
#define NCH_ (T_ / CH_)
#define LOG2E 1.4426950408889634f
#define LN2 0.6931471805599453f

// ws layout:
//   em   f32 [B][T][K]      @ 0           (41,943,040 B)
//   hist u8  [T][B][16]     @ 41943040    (16,777,216 B)
//   llh  f32 [B]            @ 58720256    (8,192 B)
//   last i32 [B]            @ 58728448    (8,192 B)

// ---------------- Phase 1: emissions = LN(x @ W^T + b) ----------------
__global__ __launch_bounds__(256) void emis_kernel(
    const float* __restrict__ x, const float* __restrict__ W,
    const float* __restrict__ bb, const float* __restrict__ gamma,
    const float* __restrict__ beta, float* __restrict__ em)
{
    __shared__ float sW[K_ * D_ + 3 * K_];
    for (int i = threadIdx.x; i < K_ * D_ + 3 * K_; i += blockDim.x) {
        float v;
        if (i < K_ * D_)             v = W[i];
        else if (i < K_ * D_ + K_)   v = bb[i - K_ * D_];
        else if (i < K_ * D_ + 2*K_) v = gamma[i - K_ * D_ - K_];
        else                         v = beta[i - K_ * D_ - 2 * K_];
        sW[i] = v;
    }
    __syncthreads();
    int row = blockIdx.x * blockDim.x + threadIdx.x;   // (b*T + t)
    if (row >= B_ * T_) return;
    const float4* xr = reinterpret_cast<const float4*>(x + (size_t)row * D_);
    float4 xv[8];
    #pragma unroll
    for (int i = 0; i < 8; i++) xv[i] = xr[i];
    float h[K_];
    #pragma unroll
    for (int k = 0; k < K_; k++) {
        float acc = 0.f;
        #pragma unroll
        for (int i = 0; i < 8; i++) {
            acc = fmaf(xv[i].x, sW[k * D_ + 4 * i + 0], acc);
            acc = fmaf(xv[i].y, sW[k * D_ + 4 * i + 1], acc);
            acc = fmaf(xv[i].z, sW[k * D_ + 4 * i + 2], acc);
            acc = fmaf(xv[i].w, sW[k * D_ + 4 * i + 3], acc);
        }
        h[k] = acc + sW[K_ * D_ + k];
    }
    float mu = 0.f;
    #pragma unroll
    for (int k = 0; k < K_; k++) mu += h[k];
    mu = mu / (float)K_;
    float var = 0.f;
    #pragma unroll
    for (int k = 0; k < K_; k++) { float d = h[k] - mu; var += d * d; }
    var = var / (float)K_;
    float r = 1.0f / sqrtf(var + LN_EPS);
    float e[K_];
    #pragma unroll
    for (int k = 0; k < K_; k++)
        e[k] = (h[k] - mu) * r * sW[K_ * D_ + K_ + k] + sW[K_ * D_ + 2 * K_ + k];
    float2* eo = reinterpret_cast<float2*>(em + (size_t)row * K_);
    #pragma unroll
    for (int k = 0; k < 5; k++) eo[k] = make_float2(e[2 * k], e[2 * k + 1]);
}

// ---------------- Phase 2: fused CRF-forward + Viterbi scan ----------------
// 1 wave per block; 4 groups of 16 lanes; group g owns sequence b0+g.
// All steady-state traffic is LDS-resident: em staged in 64-step chunks
// (double-buffered, loads issued a full chunk ahead), labels+mask staged once.
__global__ __launch_bounds__(64) void scan_kernel(
    const float* __restrict__ em, const int* __restrict__ labels,
    const int* __restrict__ mask, const float* __restrict__ startt,
    const float* __restrict__ endt, const float* __restrict__ trans,
    unsigned char* __restrict__ hist, float* __restrict__ llh_out,
    int* __restrict__ last_out)
{
    // emL: [buf*4+g] regions of 644 floats (640 used + 16B pad to de-phase banks)
    __shared__ __align__(16) float emL[2 * 4 * 644];        // 20608 B
    __shared__ __align__(16) int2  lmL[4 * 516];            // {label,mask}, 16512 B
    __shared__ __align__(16) float sh[2][4][40];            // (v,f2) interleaved
    __shared__ float str[120];                              // trans(100),start(10),end(10)

    const int lane = threadIdx.x;
    const int g    = lane >> 4;
    const int gl   = lane & 15;
    const int b0   = blockIdx.x * 4;
    const int b    = b0 + g;
    const int jj   = (gl < K_) ? gl : (K_ - 1);
    const bool isState = gl < K_;

    // ---- stage trans/start/end ----
    for (int i = lane; i < 120; i += 64) {
        float v;
        if (i < 100)      v = trans[i];
        else if (i < 110) v = startt[i - 100];
        else              v = endt[i - 110];
        str[i] = v;
    }

    // ---- stage labels+mask interleaved (global for b0..b0+3 is contiguous) ----
    const int4* glab = reinterpret_cast<const int4*>(labels + (size_t)b0 * T_);
    const int4* gmsk = reinterpret_cast<const int4*>(mask   + (size_t)b0 * T_);
    for (int i4 = lane; i4 < 512; i4 += 64) {
        int4 lv = glab[i4];
        int4 mv = gmsk[i4];
        int seq = i4 >> 7;
        int pos = (i4 & 127) << 2;
        int4* dst = reinterpret_cast<int4*>(&lmL[seq * 516 + pos]);
        dst[0] = make_int4(lv.x, mv.x, lv.y, mv.y);
        dst[1] = make_int4(lv.z, mv.z, lv.w, mv.w);
    }

    // ---- em chunk staging: lane part = float4 (il + 16*it), it=0..9 ----
    const int il = gl;
    const float* gsrc = em + (size_t)b * T_ * K_;
    float* emLg0 = emL + g * 644;
    float* emLg1 = emL + (4 + g) * 644;

    float4 rg[10];
    {   // chunk 0: load + write
        const float4* p = reinterpret_cast<const float4*>(gsrc);
        #pragma unroll
        for (int it = 0; it < 10; ++it) rg[it] = p[il + 16 * it];
        float4* d4 = reinterpret_cast<float4*>(emLg0);
        #pragma unroll
        for (int it = 0; it < 10; ++it) d4[il + 16 * it] = rg[it];
    }
    {   // issue loads for chunk 1 (land during chunk 0's 64 steps)
        const float4* p = reinterpret_cast<const float4*>(gsrc + 640);
        #pragma unroll
        for (int it = 0; it < 10; ++it) rg[it] = p[il + 16 * it];
    }
    __builtin_amdgcn_wave_barrier();

    // per-lane transition column (plain + log2-scaled)
    float Tc[K_], Tc2[K_];
    #pragma unroll
    for (int i = 0; i < K_; i++) { Tc[i] = str[i * K_ + jj]; Tc2[i] = Tc[i] * LOG2E; }

    // ---- t = 0 ----
    float em_nx = emLg0[jj];
    int2 lm0 = lmL[g * 516];
    float v = str[100 + jj] + em_nx;
    float f2 = v * LOG2E;                 // forward score in log2 domain
    float num = 0.f; int prev = 0, cnt = 0;
    if (gl == 10) {
        prev = lm0.x;
        cnt  = lm0.y;
        num  = str[100 + prev] + emLg0[prev];
    }
    sh[0][g][2 * gl]     = v;
    sh[0][g][2 * gl + 1] = f2;
    __builtin_amdgcn_wave_barrier();
    float sv[K_], sf2[K_];
    {
        const float4* r4 = reinterpret_cast<const float4*>(&sh[0][g][0]);
        #pragma unroll
        for (int q = 0; q < 5; ++q) {
            float4 t4 = r4[q];
            sv[2*q]   = t4.x; sf2[2*q]   = t4.y;
            sv[2*q+1] = t4.z; sf2[2*q+1] = t4.w;
        }
    }
    __builtin_amdgcn_wave_barrier();

    // pipelines: em prefetch depth 1 (LDS), lm depth 2 (LDS)
    em_nx = emLg0[K_ + jj];               // em[t=1][jj]
    int2 lmq0 = lmL[g * 516 + 1];
    int2 lmq1 = lmL[g * 516 + 2];

    unsigned char* hb = hist + (size_t)b * 16 + gl;

    int t = 1;
    #pragma unroll 1
    for (int c = 0; c < NCH_; ++c) {
        float* emLg = (c & 1) ? emLg1 : emLg0;
        int tcStart = (c == 0) ? 1 : 0;
        #pragma unroll 1
        for (int tc = tcStart; tc < CH_; ++tc) {
            int buf = t & 1;
            float em_t = em_nx;
            int lab_t = lmq0.x, m_t = lmq0.y;
            lmq0 = lmq1;
            // issue next-step prefetches (all LDS)
            if (tc + 1 < CH_) em_nx = emLg[(tc + 1) * K_ + jj];
            lmq1 = lmL[g * 516 + ((t + 2 < T_) ? t + 2 : T_ - 1)];
            float etag = 0.f;
            if (gl == 10) etag = emLg[tc * K_ + lab_t];

            // Viterbi (exact f32 order: add, max, first-occurrence strict >)
            float best = sv[0] + Tc[0]; int bi = 0;
            #pragma unroll
            for (int i = 1; i < K_; i++) {
                float cnd = sv[i] + Tc[i];
                bool gt = cnd > best;
                best = gt ? cnd : best;
                bi   = gt ? i : bi;
            }
            float vnew = best + em_t;

            // CRF forward in log2 domain (native v_exp/v_log)
            float a2[K_];
            #pragma unroll
            for (int i = 0; i < K_; i++) a2[i] = sf2[i] + Tc2[i];
            float mx2 = a2[0];
            #pragma unroll
            for (int i = 1; i < K_; i++) mx2 = fmaxf(mx2, a2[i]);
            float s = 0.f;
            #pragma unroll
            for (int i = 0; i < K_; i++) s += exp2f(a2[i] - mx2);
            float f2new = em_t * LOG2E + mx2 + __log2f(s);

            v  = vnew;
            f2 = (m_t > 0) ? f2new : f2;

            if (isState) hb[(size_t)t * (B_ * 16)] = (unsigned char)bi;
            if (gl == 10) {
                num += (str[prev * K_ + lab_t] + etag) * (float)m_t;
                prev = lab_t;
                cnt += m_t;
            }

            sh[buf][g][2 * gl]     = v;
            sh[buf][g][2 * gl + 1] = f2;
            __builtin_amdgcn_wave_barrier();
            const float4* r4 = reinterpret_cast<const float4*>(&sh[buf][g][0]);
            #pragma unroll
            for (int q = 0; q < 5; ++q) {
                float4 t4 = r4[q];
                sv[2*q]   = t4.x; sf2[2*q]   = t4.y;
                sv[2*q+1] = t4.z; sf2[2*q+1] = t4.w;
            }
            __builtin_amdgcn_wave_barrier();
            ++t;
        }
        // chunk boundary: commit staged regs (chunk c+1), issue loads (chunk c+2)
        if (c + 1 < NCH_) {
            float* dstL = (c & 1) ? emLg0 : emLg1;
            float4* d4 = reinterpret_cast<float4*>(dstL);
            #pragma unroll
            for (int it = 0; it < 10; ++it) d4[il + 16 * it] = rg[it];
            if (c + 2 < NCH_) {
                const float4* p = reinterpret_cast<const float4*>(gsrc + (size_t)(c + 2) * 640);
                #pragma unroll
                for (int it = 0; it < 10; ++it) rg[it] = p[il + 16 * it];
            }
            __builtin_amdgcn_wave_barrier();
            em_nx = dstL[jj];    // em for first step of next chunk
        }
    }

    // ---- epilogue ----
    if (gl == 0) {   // Viterbi terminal argmax over sv + end
        float bestv = sv[0] + str[110]; int bi = 0;
        #pragma unroll
        for (int i = 1; i < K_; i++) {
            float cnd = sv[i] + str[110 + i];
            bool gt = cnd > bestv;
            bestv = gt ? cnd : bestv;
            bi    = gt ? i : bi;
        }
        last_out[b] = bi;
    }
    if (gl == 10) {  // log_z (log2 domain) and llh
        float a2[K_];
        #pragma unroll
        for (int i = 0; i < K_; i++) a2[i] = sf2[i] + str[110 + i] * LOG2E;
        float mx2 = a2[0];
        #pragma unroll
        for (int i = 1; i < K_; i++) mx2 = fmaxf(mx2, a2[i]);
        float s = 0.f;
        #pragma unroll
        for (int i = 0; i < K_; i++) s += exp2f(a2[i] - mx2);
        float logz = (mx2 + __log2f(s)) * LN2;
        int idx = cnt - 1;
        if (idx < 0) idx = T_ - 1;       // jnp -1 wrap semantics
        int last_tag = lmL[g * 516 + idx].x;
        num += str[110 + last_tag];
        llh_out[b] = num - logz;
    }
}

// ---------------- Phase 3: backtrack (LDS transpose for coalesced stores) ----
__global__ __launch_bounds__(64) void back_kernel(
    const unsigned char* __restrict__ hist, const int* __restrict__ last,
    float* __restrict__ path)
{
    __shared__ float tile[64][65];
    const int lane = threadIdx.x;
    const int b = blockIdx.x * 64 + lane;
    const int4* h4 = reinterpret_cast<const int4*>(hist);
    int tag = last[b];
    #pragma unroll 1
    for (int c = NCH_ - 1; c >= 0; --c) {
        int t0 = c * 64;
        if (c == NCH_ - 1) tile[63][lane] = (float)tag;
        int rTop = (c == NCH_ - 1) ? 62 : 63;
        #pragma unroll 4
        for (int r = rTop; r >= 0; --r) {
            int tp = t0 + r;                       // compute tag[tp] from hist[tp+1]
            int4 vv = h4[(size_t)(tp + 1) * B_ + b];
            int w = tag >> 2;
            int word = (w == 0) ? vv.x : ((w == 1) ? vv.y : ((w == 2) ? vv.z : vv.w));
            tag = (word >> ((tag & 3) * 8)) & 0xff;
            tile[r][lane] = (float)tag;
        }
        __builtin_amdgcn_wave_barrier();
        float* pbase = path + (size_t)(blockIdx.x * 64) * T_ + t0 + lane;
        #pragma unroll 4
        for (int rr = 0; rr < 64; ++rr) {
            pbase[(size_t)rr * T_] = tile[lane][rr];
        }
        __builtin_amdgcn_wave_barrier();
    }
}

// ---------------- Phase 4: loss reduction ----------------
__global__ __launch_bounds__(256) void loss_kernel(
    const float* __restrict__ llh, float* __restrict__ out)
{
    __shared__ float red[256];
    float s = 0.f;
    for (int i = threadIdx.x; i < B_; i += 256) s += llh[i];
    red[threadIdx.x] = s;
    __syncthreads();
    for (int off = 128; off > 0; off >>= 1) {
        if (threadIdx.x < off) red[threadIdx.x] += red[threadIdx.x + off];
        __syncthreads();
    }
    if (threadIdx.x == 0) out[0] = -red[0];
}

extern "C" void kernel_launch(void* const* d_in, const int* in_sizes, int n_in,
                              void* d_out, int out_size, void* d_ws, size_t ws_size,
                              hipStream_t stream)
{
    const float* x      = (const float*)d_in[0];
    const int*   labels = (const int*)d_in[1];
    const int*   mask   = (const int*)d_in[2];
    const float* W      = (const float*)d_in[3];
    const float* bb     = (const float*)d_in[4];
    const float* gamma  = (const float*)d_in[5];
    const float* beta   = (const float*)d_in[6];
    const float* startt = (const float*)d_in[7];
    const float* endt   = (const float*)d_in[8];
    const float* trans  = (const float*)d_in[9];
    float* out = (float*)d_out;

    char* ws = (char*)d_ws;
    float*         em   = (float*)ws;
    unsigned char* hist = (unsigned char*)(ws + 41943040);
    float*         llh  = (float*)(ws + 41943040 + 16777216);
    int*           last = (int*)(ws + 41943040 + 16777216 + 8192);

    emis_kernel<<<(B_ * T_) / 256, 256, 0, stream>>>(x, W, bb, gamma, beta, em);
    scan_kernel<<<B_ / 4, 64, 0, stream>>>(em, labels, mask, startt, endt, trans,
                                           hist, llh, last);
    back_kernel<<<B_ / 64, 64, 0, stream>>>(hist, last, out + 1);
    loss_kernel<<<1, 256, 0, stream>>>(llh, out);
}